// Round 1
// baseline (762.807 us; speedup 1.0000x reference)
//
#include <hip/hip_runtime.h>
#include <math.h>

#define D 128
#define DH 64
constexpr float KREL = 3.141592653589793f / 1.5f;  // rel * (PI/1.5)

// ---- cos/sin tables for all (num_rel+1) relations ----
__global__ void k_tables(const float* __restrict__ rel_embed,
                         const float* __restrict__ loop_rel, int num_rel,
                         float* __restrict__ crt, float* __restrict__ srt) {
    int i = blockIdx.x * blockDim.x + threadIdx.x;
    int total = (num_rel + 1) * DH;
    if (i >= total) return;
    int r = i / DH, c = i % DH;
    float v = (r < num_rel) ? rel_embed[r * DH + c] : loop_rel[c];
    float ang = v * KREL;
    crt[i] = cosf(ang);
    srt[i] = sinf(ang);
}

// ---- rel_out = (rel_embed @ w_rel)  (only first num_rel rows needed) ----
__global__ void k_relout(const float* __restrict__ rel_embed,
                         const float* __restrict__ w_rel,
                         float* __restrict__ out2, int num_rel) {
    int i = blockIdx.x * blockDim.x + threadIdx.x;
    if (i >= num_rel * DH) return;
    int r = i / DH, j = i % DH;
    const float* a = rel_embed + r * DH;
    float acc = 0.f;
#pragma unroll 8
    for (int k = 0; k < DH; ++k) acc = fmaf(a[k], w_rel[k * DH + j], acc);
    out2[i] = acc;
}

// ---- degree histograms (rows of each half) ----
__global__ void k_degree(const int* __restrict__ ei, int E2,
                         unsigned* __restrict__ deg_in, unsigned* __restrict__ deg_out) {
    int e = blockIdx.x * blockDim.x + threadIdx.x;
    if (e >= E2) return;
    int row = ei[e];
    if (e < (E2 >> 1)) atomicAdd(&deg_in[row], 1u);
    else               atomicAdd(&deg_out[row], 1u);
}

// ---- per-edge: transformed+normalized message scatter-add ----
__global__ __launch_bounds__(256) void k_edge(
    const float* __restrict__ x, const int* __restrict__ ei,
    const int* __restrict__ et, int E2,
    const unsigned* __restrict__ deg_in, const unsigned* __restrict__ deg_out,
    const float* __restrict__ crt, const float* __restrict__ srt,
    float* __restrict__ T_in, float* __restrict__ T_out) {
    long long gid = (long long)blockIdx.x * blockDim.x + threadIdx.x;
    int e = (int)(gid >> 6);
    int lane = (int)(gid & 63);
    if (e >= E2) return;
    int Eh = E2 >> 1;
    bool isin = e < Eh;
    int row = ei[e];
    int col = ei[E2 + e];
    int t = et[e];
    const unsigned* deg = isin ? deg_in : deg_out;
    float* T = isin ? T_in : T_out;
    unsigned dr = deg[row], dc = deg[col];
    float norm = (dr > 0u && dc > 0u) ? rsqrtf((float)dr * (float)dc) : 0.0f;
    float re = x[(size_t)col * D + lane];
    float im = x[(size_t)col * D + DH + lane];
    float c = crt[t * DH + lane];
    float s = srt[t * DH + lane];
    float o_re = fmaf(re, c, im * s) * norm;
    float o_im = (re * s - im * c) * norm;
    unsafeAtomicAdd(&T[(size_t)row * D + lane], o_re);
    unsafeAtomicAdd(&T[(size_t)row * D + DH + lane], o_im);
}

// ---- combine: out = (T_in@w_in + T_out@w_out + phi(x,loop)@w_loop)/3 ----
#define BR 16
__global__ __launch_bounds__(256) void k_combine(
    const float* __restrict__ T_in, const float* __restrict__ T_out,
    const float* __restrict__ x,
    const float* __restrict__ w_in, const float* __restrict__ w_out,
    const float* __restrict__ w_loop,
    const float* __restrict__ crt, const float* __restrict__ srt,
    int num_rel, int num_ent, float* __restrict__ out) {
    __shared__ float lin[BR][D];
    __shared__ float lout[BR][D];
    __shared__ float lloop[BR][D];
    int tid = threadIdx.x;
    int row0 = blockIdx.x * BR;
    const float* crl = crt + (size_t)num_rel * DH;
    const float* srl = srt + (size_t)num_rel * DH;
    for (int idx = tid; idx < BR * D; idx += 256) {
        int r = idx >> 7, k = idx & 127;
        int g = row0 + r;
        float ti = 0.f, to = 0.f, tl = 0.f;
        if (g < num_ent) {
            ti = T_in[(size_t)g * D + k];
            to = T_out[(size_t)g * D + k];
            if (k < DH) {
                float re = x[(size_t)g * D + k], im = x[(size_t)g * D + DH + k];
                tl = fmaf(re, crl[k], im * srl[k]);
            } else {
                int kk = k - DH;
                float re = x[(size_t)g * D + kk], im = x[(size_t)g * D + DH + kk];
                tl = re * srl[kk] - im * crl[kk];
            }
        }
        lin[r][k] = ti; lout[r][k] = to; lloop[r][k] = tl;
    }
    __syncthreads();
    int j = tid & 127;
    int rb = tid >> 7;  // 0 or 1
    float acc[8];
#pragma unroll
    for (int i = 0; i < 8; ++i) acc[i] = 0.f;
    for (int k = 0; k < D; ++k) {
        float wi = w_in[k * D + j];
        float wo = w_out[k * D + j];
        float wl = w_loop[k * D + j];
#pragma unroll
        for (int i = 0; i < 8; ++i) {
            int r = rb + i * 2;
            acc[i] = fmaf(lin[r][k], wi, acc[i]);
            acc[i] = fmaf(lout[r][k], wo, acc[i]);
            acc[i] = fmaf(lloop[r][k], wl, acc[i]);
        }
    }
    const float third = 1.0f / 3.0f;
#pragma unroll
    for (int i = 0; i < 8; ++i) {
        int g = row0 + rb + i * 2;
        if (g < num_ent) out[(size_t)g * D + j] = acc[i] * third;
    }
}

extern "C" void kernel_launch(void* const* d_in, const int* in_sizes, int n_in,
                              void* d_out, int out_size, void* d_ws, size_t ws_size,
                              hipStream_t stream) {
    const float* x        = (const float*)d_in[0];
    const int*   ei       = (const int*)d_in[1];
    const int*   et       = (const int*)d_in[2];
    const float* rel_embed= (const float*)d_in[3];
    const float* w_loop   = (const float*)d_in[4];
    const float* w_in     = (const float*)d_in[5];
    const float* w_out    = (const float*)d_in[6];
    const float* w_rel    = (const float*)d_in[7];
    const float* loop_rel = (const float*)d_in[8];
    float* out = (float*)d_out;

    int num_ent = in_sizes[0] / D;
    int E2      = in_sizes[2];
    int num_rel = in_sizes[3] / DH;
    float* out2 = out + (size_t)num_ent * D;

    char* ws = (char*)d_ws;
    float* T_in  = (float*)ws;
    float* T_out = T_in + (size_t)num_ent * D;
    unsigned* deg_in  = (unsigned*)(T_out + (size_t)num_ent * D);
    unsigned* deg_out = deg_in + num_ent;
    float* crt = (float*)(deg_out + num_ent);
    float* srt = crt + (size_t)(num_rel + 1) * DH;

    size_t zero_bytes = (size_t)((char*)(deg_out + num_ent) - ws);
    hipMemsetAsync(d_ws, 0, zero_bytes, stream);

    int tbl = (num_rel + 1) * DH;
    k_tables<<<(tbl + 255) / 256, 256, 0, stream>>>(rel_embed, loop_rel, num_rel, crt, srt);
    k_relout<<<(num_rel * DH + 255) / 256, 256, 0, stream>>>(rel_embed, w_rel, out2, num_rel);
    k_degree<<<(E2 + 255) / 256, 256, 0, stream>>>(ei, E2, deg_in, deg_out);

    long long edge_threads = (long long)E2 * 64;
    int edge_blocks = (int)((edge_threads + 255) / 256);
    k_edge<<<edge_blocks, 256, 0, stream>>>(x, ei, et, E2, deg_in, deg_out, crt, srt, T_in, T_out);

    int cb = (num_ent + BR - 1) / BR;
    k_combine<<<cb, 256, 0, stream>>>(T_in, T_out, x, w_in, w_out, w_loop,
                                      crt, srt, num_rel, num_ent, out);
}

// Round 2
// 533.627 us; speedup vs baseline: 1.4295x; 1.4295x over previous
//
#include <hip/hip_runtime.h>
#include <math.h>

#define D 128
#define DH 64
#define CHUNK 2048
#define BR 16
constexpr float KREL = 3.141592653589793f / 1.5f;  // rel * (PI/1.5)

// ---- cos/sin tables for all (num_rel+1) relations ----
__global__ void k_tables(const float* __restrict__ rel_embed,
                         const float* __restrict__ loop_rel, int num_rel,
                         float* __restrict__ crt, float* __restrict__ srt) {
    int i = blockIdx.x * blockDim.x + threadIdx.x;
    int total = (num_rel + 1) * DH;
    if (i >= total) return;
    int r = i / DH, c = i % DH;
    float v = (r < num_rel) ? rel_embed[r * DH + c] : loop_rel[c];
    float ang = v * KREL;
    crt[i] = cosf(ang);
    srt[i] = sinf(ang);
}

// ---- rel_out = (rel_embed @ w_rel) ----
__global__ void k_relout(const float* __restrict__ rel_embed,
                         const float* __restrict__ w_rel,
                         float* __restrict__ out2, int num_rel) {
    int i = blockIdx.x * blockDim.x + threadIdx.x;
    if (i >= num_rel * DH) return;
    int r = i / DH, j = i % DH;
    const float* a = rel_embed + r * DH;
    float acc = 0.f;
#pragma unroll 8
    for (int k = 0; k < DH; ++k) acc = fmaf(a[k], w_rel[k * DH + j], acc);
    out2[i] = acc;
}

// ---- degree histogram: deg[0:N]=in-half rows, deg[N:2N]=out-half rows ----
__global__ void k_degree(const int* __restrict__ ei, int E2, int num_ent,
                         unsigned* __restrict__ deg) {
    int e = blockIdx.x * blockDim.x + threadIdx.x;
    if (e >= E2) return;
    int h = (e < (E2 >> 1)) ? 0 : 1;
    atomicAdd(&deg[h * num_ent + ei[e]], 1u);
}

// ---- hierarchical exclusive scan over 2N degrees -> rp ----
__global__ void k_scan1(const unsigned* __restrict__ deg, int n,
                        unsigned* __restrict__ rp, unsigned* __restrict__ partials) {
    __shared__ unsigned s[256];
    int tid = threadIdx.x;
    int base = blockIdx.x * CHUNK + tid * 8;
    unsigned v[8]; unsigned sum = 0;
#pragma unroll
    for (int i = 0; i < 8; ++i) { int g = base + i; v[i] = (g < n) ? deg[g] : 0u; sum += v[i]; }
    s[tid] = sum; __syncthreads();
    for (int off = 1; off < 256; off <<= 1) {
        unsigned t = (tid >= off) ? s[tid - off] : 0u;
        __syncthreads();
        s[tid] += t;
        __syncthreads();
    }
    if (tid == 255) partials[blockIdx.x] = s[255];
    unsigned run = (tid ? s[tid - 1] : 0u);
#pragma unroll
    for (int i = 0; i < 8; ++i) { int g = base + i; if (g < n) rp[g] = run; run += v[i]; }
}

__global__ void k_scan2(unsigned* __restrict__ partials, int nb) {
    __shared__ unsigned s[256];
    int tid = threadIdx.x;
    unsigned v = (tid < nb) ? partials[tid] : 0u;
    s[tid] = v; __syncthreads();
    for (int off = 1; off < 256; off <<= 1) {
        unsigned t = (tid >= off) ? s[tid - off] : 0u;
        __syncthreads();
        s[tid] += t;
        __syncthreads();
    }
    if (tid < nb) partials[tid] = (tid ? s[tid - 1] : 0u);
}

__global__ void k_scan3(unsigned* __restrict__ rp, int n,
                        const unsigned* __restrict__ partials) {
    unsigned add = partials[blockIdx.x];
    int base = blockIdx.x * CHUNK + threadIdx.x;
#pragma unroll
    for (int i = 0; i < 8; ++i) { int g = base + i * 256; if (g < n) rp[g] += add; }
}

// ---- scatter edges into CSR slots; payload (col, type, norm) packed int4 ----
__global__ void k_fill(const int* __restrict__ ei, const int* __restrict__ et,
                       int E2, int num_ent,
                       const unsigned* __restrict__ deg, const unsigned* __restrict__ rp,
                       unsigned* __restrict__ fc, int4* __restrict__ csr) {
    int e = blockIdx.x * blockDim.x + threadIdx.x;
    if (e >= E2) return;
    int Eh = E2 >> 1;
    int h = (e < Eh) ? 0 : 1;
    int row = ei[e], col = ei[E2 + e], t = et[e];
    int idx = h * num_ent + row;
    unsigned dr = deg[idx], dc = deg[h * num_ent + col];
    float nrm = (dr > 0u && dc > 0u) ? rsqrtf((float)dr * (float)dc) : 0.f;
    unsigned slot = rp[idx] + atomicAdd(&fc[idx], 1u);
    csr[slot] = make_int4(col, t, __float_as_int(nrm), 0);
}

// ---- fused gather (per-row, no atomics) + 3-way GEMM + combine ----
__global__ __launch_bounds__(256) void k_fused(
    const float* __restrict__ x, const int4* __restrict__ csr,
    const unsigned* __restrict__ rp, const unsigned* __restrict__ deg,
    const float* __restrict__ crt, const float* __restrict__ srt,
    const float* __restrict__ w_in, const float* __restrict__ w_out,
    const float* __restrict__ w_loop,
    int num_rel, int num_ent, float* __restrict__ out) {
    __shared__ float lin[BR][D];
    __shared__ float lout[BR][D];
    __shared__ float lloop[BR][D];
    int tid = threadIdx.x;
    int lane = tid & 63;
    int w = tid >> 6;
    int row0 = blockIdx.x * BR;
    const float* crl = crt + (size_t)num_rel * DH;
    const float* srl = srt + (size_t)num_rel * DH;

    for (int q = 0; q < 4; ++q) {
        int rr = w * 4 + q;
        int r = row0 + rr;
        float aire = 0.f, aiim = 0.f, aore = 0.f, aoim = 0.f, lre = 0.f, lim = 0.f;
        if (r < num_ent) {
            unsigned b = rp[r], cnt = deg[r];
            for (unsigned e = b; e < b + cnt; ++e) {
                int4 m = csr[e];
                float nm = __int_as_float(m.z);
                float re = x[(size_t)m.x * D + lane];
                float im = x[(size_t)m.x * D + DH + lane];
                float c = crt[m.y * DH + lane];
                float s = srt[m.y * DH + lane];
                aire = fmaf(nm, fmaf(re, c, im * s), aire);
                aiim = fmaf(nm, re * s - im * c, aiim);
            }
            b = rp[num_ent + r]; cnt = deg[num_ent + r];
            for (unsigned e = b; e < b + cnt; ++e) {
                int4 m = csr[e];
                float nm = __int_as_float(m.z);
                float re = x[(size_t)m.x * D + lane];
                float im = x[(size_t)m.x * D + DH + lane];
                float c = crt[m.y * DH + lane];
                float s = srt[m.y * DH + lane];
                aore = fmaf(nm, fmaf(re, c, im * s), aore);
                aoim = fmaf(nm, re * s - im * c, aoim);
            }
            float re = x[(size_t)r * D + lane], im = x[(size_t)r * D + DH + lane];
            lre = fmaf(re, crl[lane], im * srl[lane]);
            lim = re * srl[lane] - im * crl[lane];
        }
        lin[rr][lane] = aire;  lin[rr][DH + lane] = aiim;
        lout[rr][lane] = aore; lout[rr][DH + lane] = aoim;
        lloop[rr][lane] = lre; lloop[rr][DH + lane] = lim;
    }
    __syncthreads();

    int j = tid & 127;
    int rb = tid >> 7;
    float acc[8];
#pragma unroll
    for (int i = 0; i < 8; ++i) acc[i] = 0.f;
    for (int k0 = 0; k0 < D; k0 += 4) {
        float4 va[8], vb[8], vc[8];
#pragma unroll
        for (int i = 0; i < 8; ++i) {
            int r = rb + 2 * i;
            va[i] = *reinterpret_cast<const float4*>(&lin[r][k0]);
            vb[i] = *reinterpret_cast<const float4*>(&lout[r][k0]);
            vc[i] = *reinterpret_cast<const float4*>(&lloop[r][k0]);
        }
#pragma unroll
        for (int kk = 0; kk < 4; ++kk) {
            float wi = w_in[(k0 + kk) * D + j];
            float wo = w_out[(k0 + kk) * D + j];
            float wl = w_loop[(k0 + kk) * D + j];
#pragma unroll
            for (int i = 0; i < 8; ++i) {
                float a = kk == 0 ? va[i].x : kk == 1 ? va[i].y : kk == 2 ? va[i].z : va[i].w;
                float bvt = kk == 0 ? vb[i].x : kk == 1 ? vb[i].y : kk == 2 ? vb[i].z : vb[i].w;
                float cv = kk == 0 ? vc[i].x : kk == 1 ? vc[i].y : kk == 2 ? vc[i].z : vc[i].w;
                acc[i] = fmaf(a, wi, acc[i]);
                acc[i] = fmaf(bvt, wo, acc[i]);
                acc[i] = fmaf(cv, wl, acc[i]);
            }
        }
    }
    const float third = 1.0f / 3.0f;
#pragma unroll
    for (int i = 0; i < 8; ++i) {
        int g = row0 + rb + 2 * i;
        if (g < num_ent) out[(size_t)g * D + j] = acc[i] * third;
    }
}

extern "C" void kernel_launch(void* const* d_in, const int* in_sizes, int n_in,
                              void* d_out, int out_size, void* d_ws, size_t ws_size,
                              hipStream_t stream) {
    const float* x         = (const float*)d_in[0];
    const int*   ei        = (const int*)d_in[1];
    const int*   et        = (const int*)d_in[2];
    const float* rel_embed = (const float*)d_in[3];
    const float* w_loop    = (const float*)d_in[4];
    const float* w_in      = (const float*)d_in[5];
    const float* w_out     = (const float*)d_in[6];
    const float* w_rel     = (const float*)d_in[7];
    const float* loop_rel  = (const float*)d_in[8];
    float* out = (float*)d_out;

    int num_ent = in_sizes[0] / D;
    int E2      = in_sizes[2];
    int num_rel = in_sizes[3] / DH;
    float* out2 = out + (size_t)num_ent * D;

    int n2 = 2 * num_ent;
    char* ws = (char*)d_ws;
    unsigned* deg = (unsigned*)ws;                 // 2N
    unsigned* fc  = deg + n2;                      // 2N  (adjacent to deg for one memset)
    unsigned* rp  = fc + n2;                       // 2N
    unsigned* partials = rp + n2;                  // 256
    size_t off = (size_t)(3 * n2 + 256) * sizeof(unsigned);
    off = (off + 15) & ~(size_t)15;
    int4* csr = (int4*)(ws + off);                 // E2 int4
    float* crt = (float*)(csr + E2);               // (num_rel+1)*DH
    float* srt = crt + (size_t)(num_rel + 1) * DH;

    // zero deg + fc only
    hipMemsetAsync(deg, 0, (size_t)2 * n2 * sizeof(unsigned), stream);

    int tbl = (num_rel + 1) * DH;
    k_tables<<<(tbl + 255) / 256, 256, 0, stream>>>(rel_embed, loop_rel, num_rel, crt, srt);
    k_relout<<<(num_rel * DH + 255) / 256, 256, 0, stream>>>(rel_embed, w_rel, out2, num_rel);
    k_degree<<<(E2 + 255) / 256, 256, 0, stream>>>(ei, E2, num_ent, deg);

    int nb1 = (n2 + CHUNK - 1) / CHUNK;
    k_scan1<<<nb1, 256, 0, stream>>>(deg, n2, rp, partials);
    k_scan2<<<1, 256, 0, stream>>>(partials, nb1);
    k_scan3<<<nb1, 256, 0, stream>>>(rp, n2, partials);

    k_fill<<<(E2 + 255) / 256, 256, 0, stream>>>(ei, et, E2, num_ent, deg, rp, fc, csr);

    int cb = (num_ent + BR - 1) / BR;
    k_fused<<<cb, 256, 0, stream>>>(x, csr, rp, deg, crt, srt,
                                    w_in, w_out, w_loop, num_rel, num_ent, out);
}

// Round 3
// 448.795 us; speedup vs baseline: 1.6997x; 1.1890x over previous
//
#include <hip/hip_runtime.h>
#include <math.h>

#define D 128
#define DH 64
#define CHUNK 2048
#define BR 16
#define EPW 16
constexpr float KREL = 3.141592653589793f / 1.5f;  // rel * (PI/1.5)

// ---- packed cos/sin table: pt[r*128 + 2c] = cos, pt[r*128 + 2c + 1] = sin ----
__global__ void k_tables(const float* __restrict__ rel_embed,
                         const float* __restrict__ loop_rel, int num_rel,
                         float* __restrict__ pt) {
    int i = blockIdx.x * blockDim.x + threadIdx.x;
    int total = (num_rel + 1) * DH;
    if (i >= total) return;
    int r = i / DH, c = i % DH;
    float v = (r < num_rel) ? rel_embed[r * DH + c] : loop_rel[c];
    float ang = v * KREL;
    pt[(size_t)r * D + 2 * c]     = cosf(ang);
    pt[(size_t)r * D + 2 * c + 1] = sinf(ang);
}

// ---- rel_out = (rel_embed @ w_rel) ----
__global__ void k_relout(const float* __restrict__ rel_embed,
                         const float* __restrict__ w_rel,
                         float* __restrict__ out2, int num_rel) {
    int i = blockIdx.x * blockDim.x + threadIdx.x;
    if (i >= num_rel * DH) return;
    int r = i / DH, j = i % DH;
    const float* a = rel_embed + r * DH;
    float acc = 0.f;
#pragma unroll 8
    for (int k = 0; k < DH; ++k) acc = fmaf(a[k], w_rel[k * DH + j], acc);
    out2[i] = acc;
}

// ---- degree histogram over 2N virtual rows (in-half then out-half) ----
__global__ void k_degree(const int* __restrict__ ei, int E2, int num_ent,
                         unsigned* __restrict__ deg) {
    int e = blockIdx.x * blockDim.x + threadIdx.x;
    if (e >= E2) return;
    int h = (e < (E2 >> 1)) ? 0 : 1;
    atomicAdd(&deg[h * num_ent + ei[e]], 1u);
}

// ---- hierarchical exclusive scan over 2N degrees -> rp ----
__global__ void k_scan1(const unsigned* __restrict__ deg, int n,
                        unsigned* __restrict__ rp, unsigned* __restrict__ partials) {
    __shared__ unsigned s[256];
    int tid = threadIdx.x;
    int base = blockIdx.x * CHUNK + tid * 8;
    unsigned v[8]; unsigned sum = 0;
#pragma unroll
    for (int i = 0; i < 8; ++i) { int g = base + i; v[i] = (g < n) ? deg[g] : 0u; sum += v[i]; }
    s[tid] = sum; __syncthreads();
    for (int off = 1; off < 256; off <<= 1) {
        unsigned t = (tid >= off) ? s[tid - off] : 0u;
        __syncthreads();
        s[tid] += t;
        __syncthreads();
    }
    if (tid == 255) partials[blockIdx.x] = s[255];
    unsigned run = (tid ? s[tid - 1] : 0u);
#pragma unroll
    for (int i = 0; i < 8; ++i) { int g = base + i; if (g < n) rp[g] = run; run += v[i]; }
}

__global__ void k_scan2(unsigned* __restrict__ partials, int nb) {
    __shared__ unsigned s[256];
    int tid = threadIdx.x;
    unsigned v = (tid < nb) ? partials[tid] : 0u;
    s[tid] = v; __syncthreads();
    for (int off = 1; off < 256; off <<= 1) {
        unsigned t = (tid >= off) ? s[tid - off] : 0u;
        __syncthreads();
        s[tid] += t;
        __syncthreads();
    }
    if (tid < nb) partials[tid] = (tid ? s[tid - 1] : 0u);
}

__global__ void k_scan3(unsigned* __restrict__ rp, int n,
                        const unsigned* __restrict__ partials) {
    unsigned add = partials[blockIdx.x];
    int base = blockIdx.x * CHUNK + threadIdx.x;
#pragma unroll
    for (int i = 0; i < 8; ++i) { int g = base + i * 256; if (g < n) rp[g] += add; }
}

// ---- scatter edges into CSR slots; payload (col, type, norm, trow) ----
__global__ void k_fill(const int* __restrict__ ei, const int* __restrict__ et,
                       int E2, int num_ent,
                       const unsigned* __restrict__ deg, const unsigned* __restrict__ rp,
                       unsigned* __restrict__ fc, int4* __restrict__ csr) {
    int e = blockIdx.x * blockDim.x + threadIdx.x;
    if (e >= E2) return;
    int Eh = E2 >> 1;
    int h = (e < Eh) ? 0 : 1;
    int row = ei[e], col = ei[E2 + e], t = et[e];
    int idx = h * num_ent + row;
    unsigned dr = deg[idx], dc = deg[h * num_ent + col];
    float nrm = (dr > 0u && dc > 0u) ? rsqrtf((float)dr * (float)dc) : 0.f;
    unsigned slot = rp[idx] + atomicAdd(&fc[idx], 1u);
    csr[slot] = make_int4(col, t, __float_as_int(nrm), idx);
}

// ---- edge-parallel segmented gather: 1 wave = EPW consecutive CSR slots ----
// Rows fully inside a chunk -> plain store; rows spanning chunks -> atomic.
__global__ __launch_bounds__(256) void k_gather(
    const float* __restrict__ x, const int4* __restrict__ csr, int E2,
    const float* __restrict__ pt, float* __restrict__ T) {
    int gwave = (int)((blockIdx.x * 256u + threadIdx.x) >> 6);
    int lane = threadIdx.x & 63;
    long long s0 = (long long)gwave * EPW;
    if (s0 >= E2) return;
    int n = (int)min((long long)EPW, (long long)E2 - s0);
    const int* csr_i = (const int*)csr;

    int4 m[EPW];
#pragma unroll
    for (int k = 0; k < EPW; ++k) {
        m[k] = csr[s0 + (k < n ? k : n - 1)];
        if (k >= n) m[k].z = 0;  // padded edges contribute 0
    }
    int prow = (s0 > 0)      ? csr_i[(s0 - 1) * 4 + 3] : -1;
    int nrow = (s0 + n < E2) ? csr_i[(s0 + n) * 4 + 3] : -1;

    float re[EPW], im[EPW]; float2 cs[EPW];
#pragma unroll
    for (int k = 0; k < EPW; ++k) {
        const float* xr = x + (size_t)m[k].x * D;
        re[k] = xr[lane];
        im[k] = xr[DH + lane];
        cs[k] = *reinterpret_cast<const float2*>(pt + (size_t)m[k].y * D + 2 * lane);
    }

    float a_re = 0.f, a_im = 0.f;
    int cur = m[0].w;
    bool openL = (prow == cur);
#pragma unroll
    for (int k = 0; k < EPW; ++k) {
        int trow = m[k].w;
        if (trow != cur) {  // wave-uniform
            float* dst = T + (size_t)cur * D;
            if (openL) {
                unsafeAtomicAdd(dst + lane, a_re);
                unsafeAtomicAdd(dst + DH + lane, a_im);
            } else {
                dst[lane] = a_re;
                dst[DH + lane] = a_im;
            }
            a_re = a_im = 0.f; cur = trow; openL = false;
        }
        float nm = __int_as_float(m[k].z);
        float nre = nm * re[k], nim = nm * im[k];
        a_re = fmaf(nre, cs[k].x, fmaf(nim, cs[k].y, a_re));
        a_im = fmaf(nre, cs[k].y, fmaf(-nim, cs[k].x, a_im));
    }
    bool openR = (nrow == cur);
    float* dst = T + (size_t)cur * D;
    if (openL || openR) {
        unsafeAtomicAdd(dst + lane, a_re);
        unsafeAtomicAdd(dst + DH + lane, a_im);
    } else {
        dst[lane] = a_re;
        dst[DH + lane] = a_im;
    }
}

// ---- combine: out = (T_in@w_in + T_out@w_out + phi(x,loop)@w_loop)/3 ----
__global__ __launch_bounds__(256) void k_combine(
    const float* __restrict__ T, const float* __restrict__ x,
    const float* __restrict__ w_in, const float* __restrict__ w_out,
    const float* __restrict__ w_loop, const float* __restrict__ pt,
    int num_rel, int num_ent, float* __restrict__ out) {
    __shared__ float lin[BR][D];
    __shared__ float lout[BR][D];
    __shared__ float lloop[BR][D];
    int tid = threadIdx.x;
    int row0 = blockIdx.x * BR;
    const float* ptL = pt + (size_t)num_rel * D;

    for (int idx = tid; idx < BR * D; idx += 256) {
        int r = idx >> 7, k = idx & 127;
        int g = row0 + r;
        float ti = 0.f, to = 0.f, tl = 0.f;
        if (g < num_ent) {
            ti = T[(size_t)g * D + k];
            to = T[(size_t)(num_ent + g) * D + k];
            int kk = k & (DH - 1);
            float2 cssv = *reinterpret_cast<const float2*>(ptL + 2 * kk);
            float rv = x[(size_t)g * D + kk], iv = x[(size_t)g * D + DH + kk];
            tl = (k < DH) ? fmaf(rv, cssv.x, iv * cssv.y)
                          : (rv * cssv.y - iv * cssv.x);
        }
        lin[r][k] = ti; lout[r][k] = to; lloop[r][k] = tl;
    }
    __syncthreads();

    int j = tid & 127;
    int rb = tid >> 7;
    float acc[8];
#pragma unroll
    for (int i = 0; i < 8; ++i) acc[i] = 0.f;
    for (int k0 = 0; k0 < D; k0 += 4) {
        float4 va[8], vb[8], vc[8];
#pragma unroll
        for (int i = 0; i < 8; ++i) {
            int r = rb + 2 * i;
            va[i] = *reinterpret_cast<const float4*>(&lin[r][k0]);
            vb[i] = *reinterpret_cast<const float4*>(&lout[r][k0]);
            vc[i] = *reinterpret_cast<const float4*>(&lloop[r][k0]);
        }
#pragma unroll
        for (int kk = 0; kk < 4; ++kk) {
            float wi = w_in[(k0 + kk) * D + j];
            float wo = w_out[(k0 + kk) * D + j];
            float wl = w_loop[(k0 + kk) * D + j];
#pragma unroll
            for (int i = 0; i < 8; ++i) {
                float a = kk == 0 ? va[i].x : kk == 1 ? va[i].y : kk == 2 ? va[i].z : va[i].w;
                float bvt = kk == 0 ? vb[i].x : kk == 1 ? vb[i].y : kk == 2 ? vb[i].z : vb[i].w;
                float cv = kk == 0 ? vc[i].x : kk == 1 ? vc[i].y : kk == 2 ? vc[i].z : vc[i].w;
                acc[i] = fmaf(a, wi, acc[i]);
                acc[i] = fmaf(bvt, wo, acc[i]);
                acc[i] = fmaf(cv, wl, acc[i]);
            }
        }
    }
    const float third = 1.0f / 3.0f;
#pragma unroll
    for (int i = 0; i < 8; ++i) {
        int g = row0 + rb + 2 * i;
        if (g < num_ent) out[(size_t)g * D + j] = acc[i] * third;
    }
}

extern "C" void kernel_launch(void* const* d_in, const int* in_sizes, int n_in,
                              void* d_out, int out_size, void* d_ws, size_t ws_size,
                              hipStream_t stream) {
    const float* x         = (const float*)d_in[0];
    const int*   ei        = (const int*)d_in[1];
    const int*   et        = (const int*)d_in[2];
    const float* rel_embed = (const float*)d_in[3];
    const float* w_loop    = (const float*)d_in[4];
    const float* w_in      = (const float*)d_in[5];
    const float* w_out     = (const float*)d_in[6];
    const float* w_rel     = (const float*)d_in[7];
    const float* loop_rel  = (const float*)d_in[8];
    float* out = (float*)d_out;

    int num_ent = in_sizes[0] / D;
    int E2      = in_sizes[2];
    int num_rel = in_sizes[3] / DH;
    float* out2 = out + (size_t)num_ent * D;

    int n2 = 2 * num_ent;
    char* ws = (char*)d_ws;
    unsigned* deg = (unsigned*)ws;                 // 2N
    unsigned* fc  = deg + n2;                      // 2N (adjacent: one memset)
    unsigned* rp  = fc + n2;                       // 2N
    unsigned* partials = rp + n2;                  // 256
    size_t off = (size_t)(3 * n2 + 256) * sizeof(unsigned);
    off = (off + 15) & ~(size_t)15;
    int4* csr = (int4*)(ws + off);                 // E2 int4
    float* pt = (float*)(csr + E2);                // (num_rel+1)*128
    float* T  = pt + (size_t)(num_rel + 1) * D;    // 2N*128

    hipMemsetAsync(deg, 0, (size_t)2 * n2 * sizeof(unsigned), stream);
    hipMemsetAsync(T, 0, (size_t)n2 * D * sizeof(float), stream);

    int tbl = (num_rel + 1) * DH;
    k_tables<<<(tbl + 255) / 256, 256, 0, stream>>>(rel_embed, loop_rel, num_rel, pt);
    k_relout<<<(num_rel * DH + 255) / 256, 256, 0, stream>>>(rel_embed, w_rel, out2, num_rel);
    k_degree<<<(E2 + 255) / 256, 256, 0, stream>>>(ei, E2, num_ent, deg);

    int nb1 = (n2 + CHUNK - 1) / CHUNK;
    k_scan1<<<nb1, 256, 0, stream>>>(deg, n2, rp, partials);
    k_scan2<<<1, 256, 0, stream>>>(partials, nb1);
    k_scan3<<<nb1, 256, 0, stream>>>(rp, n2, partials);

    k_fill<<<(E2 + 255) / 256, 256, 0, stream>>>(ei, et, E2, num_ent, deg, rp, fc, csr);

    long long nwaves = ((long long)E2 + EPW - 1) / EPW;
    int gblocks = (int)((nwaves * 64 + 255) / 256);
    k_gather<<<gblocks, 256, 0, stream>>>(x, csr, E2, pt, T);

    int cb = (num_ent + BR - 1) / BR;
    k_combine<<<cb, 256, 0, stream>>>(T, x, w_in, w_out, w_loop, pt,
                                      num_rel, num_ent, out);
}

// Round 4
// 308.419 us; speedup vs baseline: 2.4733x; 1.4551x over previous
//
#include <hip/hip_runtime.h>
#include <hip/hip_bf16.h>
#include <math.h>

#define D 128
#define DH 64
#define CHUNK 2048
#define EPW 16
typedef __attribute__((ext_vector_type(8))) short bf16x8;
typedef __attribute__((ext_vector_type(4))) float f32x4;
constexpr float KREL = 3.141592653589793f / 1.5f;  // rel * (PI/1.5)

// ---- packed cos/sin table: pt[r*128 + 2c] = cos, pt[r*128 + 2c + 1] = sin ----
__global__ void k_tables(const float* __restrict__ rel_embed,
                         const float* __restrict__ loop_rel, int num_rel,
                         float* __restrict__ pt) {
    int i = blockIdx.x * blockDim.x + threadIdx.x;
    int total = (num_rel + 1) * DH;
    if (i >= total) return;
    int r = i / DH, c = i % DH;
    float v = (r < num_rel) ? rel_embed[r * DH + c] : loop_rel[c];
    float ang = v * KREL;
    pt[(size_t)r * D + 2 * c]     = cosf(ang);
    pt[(size_t)r * D + 2 * c + 1] = sinf(ang);
}

// ---- rel_out = (rel_embed @ w_rel) ----
__global__ void k_relout(const float* __restrict__ rel_embed,
                         const float* __restrict__ w_rel,
                         float* __restrict__ out2, int num_rel) {
    int i = blockIdx.x * blockDim.x + threadIdx.x;
    if (i >= num_rel * DH) return;
    int r = i / DH, j = i % DH;
    const float* a = rel_embed + r * DH;
    float acc = 0.f;
#pragma unroll 8
    for (int k = 0; k < DH; ++k) acc = fmaf(a[k], w_rel[k * DH + j], acc);
    out2[i] = acc;
}

// ---- pre-swizzle weights into MFMA B-fragment order (bf16) ----
// frag id fid = (plane*4 + kt)*8 + ct ; element = fid*512 + lane*8 + j
// value = bf16( Wp[(kt*32 + (lane>>4)*8 + j)*128 + ct*16 + (lane&15)] )
__global__ void k_wswz(const float* __restrict__ w_in, const float* __restrict__ w_out,
                       const float* __restrict__ w_loop, unsigned short* __restrict__ Bsw) {
    int i = blockIdx.x * blockDim.x + threadIdx.x;
    if (i >= 3 * 4 * 8 * 512) return;
    int j = i & 7;
    int lane = (i >> 3) & 63;
    int fid = i >> 9;
    int ct = fid & 7;
    int kt = (fid >> 3) & 3;
    int plane = fid >> 5;
    const float* Wp = (plane == 0) ? w_in : (plane == 1) ? w_out : w_loop;
    int k = kt * 32 + ((lane >> 4) << 3) + j;
    int col = ct * 16 + (lane & 15);
    __hip_bfloat16 h = __float2bfloat16(Wp[k * 128 + col]);
    Bsw[i] = __builtin_bit_cast(unsigned short, h);
}

// ---- degree histogram over 2N virtual rows (in-half then out-half) ----
__global__ void k_degree(const int* __restrict__ ei, int E2, int num_ent,
                         unsigned* __restrict__ deg) {
    int e = blockIdx.x * blockDim.x + threadIdx.x;
    if (e >= E2) return;
    int h = (e < (E2 >> 1)) ? 0 : 1;
    atomicAdd(&deg[h * num_ent + ei[e]], 1u);
}

// ---- hierarchical exclusive scan over 2N degrees -> rp ----
__global__ void k_scan1(const unsigned* __restrict__ deg, int n,
                        unsigned* __restrict__ rp, unsigned* __restrict__ partials) {
    __shared__ unsigned s[256];
    int tid = threadIdx.x;
    int base = blockIdx.x * CHUNK + tid * 8;
    unsigned v[8]; unsigned sum = 0;
#pragma unroll
    for (int i = 0; i < 8; ++i) { int g = base + i; v[i] = (g < n) ? deg[g] : 0u; sum += v[i]; }
    s[tid] = sum; __syncthreads();
    for (int off = 1; off < 256; off <<= 1) {
        unsigned t = (tid >= off) ? s[tid - off] : 0u;
        __syncthreads();
        s[tid] += t;
        __syncthreads();
    }
    if (tid == 255) partials[blockIdx.x] = s[255];
    unsigned run = (tid ? s[tid - 1] : 0u);
#pragma unroll
    for (int i = 0; i < 8; ++i) { int g = base + i; if (g < n) rp[g] = run; run += v[i]; }
}

__global__ void k_scan2(unsigned* __restrict__ partials, int nb) {
    __shared__ unsigned s[256];
    int tid = threadIdx.x;
    unsigned v = (tid < nb) ? partials[tid] : 0u;
    s[tid] = v; __syncthreads();
    for (int off = 1; off < 256; off <<= 1) {
        unsigned t = (tid >= off) ? s[tid - off] : 0u;
        __syncthreads();
        s[tid] += t;
        __syncthreads();
    }
    if (tid < nb) partials[tid] = (tid ? s[tid - 1] : 0u);
}

__global__ void k_scan3(unsigned* __restrict__ rp, int n,
                        const unsigned* __restrict__ partials) {
    unsigned add = partials[blockIdx.x];
    int base = blockIdx.x * CHUNK + threadIdx.x;
#pragma unroll
    for (int i = 0; i < 8; ++i) { int g = base + i * 256; if (g < n) rp[g] += add; }
}

// ---- scatter edges into CSR slots; payload (col, type, norm, vrow) ----
__global__ void k_fill(const int* __restrict__ ei, const int* __restrict__ et,
                       int E2, int num_ent,
                       const unsigned* __restrict__ deg, const unsigned* __restrict__ rp,
                       unsigned* __restrict__ fc, int4* __restrict__ csr) {
    int e = blockIdx.x * blockDim.x + threadIdx.x;
    if (e >= E2) return;
    int Eh = E2 >> 1;
    int h = (e < Eh) ? 0 : 1;
    int row = ei[e], col = ei[E2 + e], t = et[e];
    int idx = h * num_ent + row;
    unsigned dr = deg[idx], dc = deg[h * num_ent + col];
    float nrm = (dr > 0u && dc > 0u) ? rsqrtf((float)dr * (float)dc) : 0.f;
    unsigned slot = rp[idx] + atomicAdd(&fc[idx], 1u);
    csr[slot] = make_int4(col, t, __float_as_int(nrm), idx);
}

// ---- edge-parallel segmented gather: 1 wave = EPW consecutive CSR slots ----
__global__ __launch_bounds__(256) void k_gather(
    const float* __restrict__ x, const int4* __restrict__ csr, int E2,
    const float* __restrict__ pt, float* __restrict__ T) {
    int gwave = (int)((blockIdx.x * 256u + threadIdx.x) >> 6);
    int lane = threadIdx.x & 63;
    long long s0 = (long long)gwave * EPW;
    if (s0 >= E2) return;
    int n = (int)min((long long)EPW, (long long)E2 - s0);
    const int* csr_i = (const int*)csr;

    int4 m[EPW];
#pragma unroll
    for (int k = 0; k < EPW; ++k) {
        m[k] = csr[s0 + (k < n ? k : n - 1)];
        if (k >= n) m[k].z = 0;  // padded edges contribute 0
    }
    int prow = (s0 > 0)      ? csr_i[(s0 - 1) * 4 + 3] : -1;
    int nrow = (s0 + n < E2) ? csr_i[(s0 + n) * 4 + 3] : -1;

    float re[EPW], im[EPW]; float2 cs[EPW];
#pragma unroll
    for (int k = 0; k < EPW; ++k) {
        const float* xr = x + (size_t)m[k].x * D;
        re[k] = xr[lane];
        im[k] = xr[DH + lane];
        cs[k] = *reinterpret_cast<const float2*>(pt + (size_t)m[k].y * D + 2 * lane);
    }

    float a_re = 0.f, a_im = 0.f;
    int cur = m[0].w;
    bool openL = (prow == cur);
#pragma unroll
    for (int k = 0; k < EPW; ++k) {
        int trow = m[k].w;
        if (trow != cur) {  // wave-uniform
            float* dst = T + (size_t)cur * D;
            if (openL) {
                unsafeAtomicAdd(dst + lane, a_re);
                unsafeAtomicAdd(dst + DH + lane, a_im);
            } else {
                dst[lane] = a_re;
                dst[DH + lane] = a_im;
            }
            a_re = a_im = 0.f; cur = trow; openL = false;
        }
        float nm = __int_as_float(m[k].z);
        float nre = nm * re[k], nim = nm * im[k];
        a_re = fmaf(nre, cs[k].x, fmaf(nim, cs[k].y, a_re));
        a_im = fmaf(nre, cs[k].y, fmaf(-nim, cs[k].x, a_im));
    }
    bool openR = (nrow == cur);
    float* dst = T + (size_t)cur * D;
    if (openL || openR) {
        unsafeAtomicAdd(dst + lane, a_re);
        unsafeAtomicAdd(dst + DH + lane, a_im);
    } else {
        dst[lane] = a_re;
        dst[DH + lane] = a_im;
    }
}

// ---- MFMA combine: out = ([T_in|T_out|phi(x)] @ [w_in;w_out;w_loop]) / 3 ----
// A is split exactly into bf16 hi+lo (2 MFMAs); only weight bf16 rounding remains.
__global__ __launch_bounds__(256) void k_combine(
    const float* __restrict__ T, const float* __restrict__ x,
    const unsigned short* __restrict__ Bsw, const float* __restrict__ pt,
    int num_rel, int num_ent, float* __restrict__ out) {
    int tid = threadIdx.x;
    int lane = tid & 63;
    int wid = tid >> 6;
    int base = blockIdx.x * 64 + wid * 16;
    int arow = base + (lane & 15);
    if (arow >= num_ent) arow = num_ent - 1;
    int khi = (lane >> 4) << 3;  // 0,8,16,24

    f32x4 acc[8];
    f32x4 zero = {0.f, 0.f, 0.f, 0.f};
#pragma unroll
    for (int i = 0; i < 8; ++i) acc[i] = zero;

    const float* ptL = pt + (size_t)num_rel * D;

    auto run_kt = [&](const float* av, int fid_base) {
        bf16x8 ah, al;
#pragma unroll
        for (int i = 0; i < 8; ++i) {
            unsigned b = __float_as_uint(av[i]);
            ah[i] = (short)(b >> 16);
            float hf = __uint_as_float(b & 0xFFFF0000u);
            al[i] = (short)(__float_as_uint(av[i] - hf) >> 16);
        }
#pragma unroll
        for (int ct = 0; ct < 8; ++ct) {
            const unsigned short* bp = Bsw + (((size_t)fid_base * 8 + ct) << 9) + (lane << 3);
            bf16x8 bfrag = *reinterpret_cast<const bf16x8*>(bp);
            acc[ct] = __builtin_amdgcn_mfma_f32_16x16x32_bf16(ah, bfrag, acc[ct], 0, 0, 0);
            acc[ct] = __builtin_amdgcn_mfma_f32_16x16x32_bf16(al, bfrag, acc[ct], 0, 0, 0);
        }
    };

    // planes 0,1: T_in / T_out (stored as [2N][128])
#pragma unroll
    for (int plane = 0; plane < 2; ++plane) {
        const float* Ab = T + ((size_t)plane * num_ent + arow) * D;
#pragma unroll
        for (int kt = 0; kt < 4; ++kt) {
            float4 q0 = *reinterpret_cast<const float4*>(Ab + kt * 32 + khi);
            float4 q1 = *reinterpret_cast<const float4*>(Ab + kt * 32 + khi + 4);
            float av[8] = {q0.x, q0.y, q0.z, q0.w, q1.x, q1.y, q1.z, q1.w};
            run_kt(av, plane * 4 + kt);
        }
    }
    // plane 2: loop transform computed on the fly
    {
        const float* xr = x + (size_t)arow * D;
#pragma unroll
        for (int kt = 0; kt < 4; ++kt) {
            int kp = ((kt & 1) << 5) + khi;  // k' in [0,64)
            float4 r0 = *reinterpret_cast<const float4*>(xr + kp);
            float4 r1 = *reinterpret_cast<const float4*>(xr + kp + 4);
            float4 i0 = *reinterpret_cast<const float4*>(xr + DH + kp);
            float4 i1 = *reinterpret_cast<const float4*>(xr + DH + kp + 4);
            float rr[8] = {r0.x, r0.y, r0.z, r0.w, r1.x, r1.y, r1.z, r1.w};
            float ii[8] = {i0.x, i0.y, i0.z, i0.w, i1.x, i1.y, i1.z, i1.w};
            float av[8];
#pragma unroll
            for (int j = 0; j < 8; ++j) {
                float2 cs = *reinterpret_cast<const float2*>(ptL + 2 * (kp + j));
                av[j] = (kt < 2) ? fmaf(rr[j], cs.x, ii[j] * cs.y)
                                 : (rr[j] * cs.y - ii[j] * cs.x);
            }
            run_kt(av, 8 + kt);
        }
    }
    // store: C/D layout col=lane&15, row=(lane>>4)*4+reg
    const float third = 1.0f / 3.0f;
    int rbase = base + ((lane >> 4) << 2);
    int colb = lane & 15;
#pragma unroll
    for (int ct = 0; ct < 8; ++ct) {
#pragma unroll
        for (int jj = 0; jj < 4; ++jj) {
            int g = rbase + jj;
            if (g < num_ent) out[(size_t)g * D + ct * 16 + colb] = acc[ct][jj] * third;
        }
    }
}

extern "C" void kernel_launch(void* const* d_in, const int* in_sizes, int n_in,
                              void* d_out, int out_size, void* d_ws, size_t ws_size,
                              hipStream_t stream) {
    const float* x         = (const float*)d_in[0];
    const int*   ei        = (const int*)d_in[1];
    const int*   et        = (const int*)d_in[2];
    const float* rel_embed = (const float*)d_in[3];
    const float* w_loop    = (const float*)d_in[4];
    const float* w_in      = (const float*)d_in[5];
    const float* w_out     = (const float*)d_in[6];
    const float* w_rel     = (const float*)d_in[7];
    const float* loop_rel  = (const float*)d_in[8];
    float* out = (float*)d_out;

    int num_ent = in_sizes[0] / D;
    int E2      = in_sizes[2];
    int num_rel = in_sizes[3] / DH;
    float* out2 = out + (size_t)num_ent * D;

    int n2 = 2 * num_ent;
    char* ws = (char*)d_ws;
    unsigned* deg = (unsigned*)ws;                 // 2N
    unsigned* fc  = deg + n2;                      // 2N (adjacent: one memset)
    unsigned* rp  = fc + n2;                       // 2N
    unsigned* partials = rp + n2;                  // 256
    size_t off = (size_t)(3 * n2 + 256) * sizeof(unsigned);
    off = (off + 15) & ~(size_t)15;
    int4* csr = (int4*)(ws + off);                 // E2 int4
    float* pt = (float*)(csr + E2);                // (num_rel+1)*128 floats
    unsigned short* Bsw = (unsigned short*)(pt + (size_t)(num_rel + 1) * D);  // 3*4*8*512
    float* T = (float*)(Bsw + 3 * 4 * 8 * 512);    // 2N*128 floats

    hipMemsetAsync(deg, 0, (size_t)2 * n2 * sizeof(unsigned), stream);
    hipMemsetAsync(T, 0, (size_t)n2 * D * sizeof(float), stream);

    int tbl = (num_rel + 1) * DH;
    k_tables<<<(tbl + 255) / 256, 256, 0, stream>>>(rel_embed, loop_rel, num_rel, pt);
    k_relout<<<(num_rel * DH + 255) / 256, 256, 0, stream>>>(rel_embed, w_rel, out2, num_rel);
    k_wswz<<<(3 * 4 * 8 * 512 + 255) / 256, 256, 0, stream>>>(w_in, w_out, w_loop, Bsw);
    k_degree<<<(E2 + 255) / 256, 256, 0, stream>>>(ei, E2, num_ent, deg);

    int nb1 = (n2 + CHUNK - 1) / CHUNK;
    k_scan1<<<nb1, 256, 0, stream>>>(deg, n2, rp, partials);
    k_scan2<<<1, 256, 0, stream>>>(partials, nb1);
    k_scan3<<<nb1, 256, 0, stream>>>(rp, n2, partials);

    k_fill<<<(E2 + 255) / 256, 256, 0, stream>>>(ei, et, E2, num_ent, deg, rp, fc, csr);

    long long nwaves = ((long long)E2 + EPW - 1) / EPW;
    int gblocks = (int)((nwaves * 64 + 255) / 256);
    k_gather<<<gblocks, 256, 0, stream>>>(x, csr, E2, pt, T);

    int cb = (num_ent + 63) / 64;
    k_combine<<<cb, 256, 0, stream>>>(T, x, Bsw, pt, num_rel, num_ent, out);
}

// Round 8
// 294.043 us; speedup vs baseline: 2.5942x; 1.0489x over previous
//
#include <hip/hip_runtime.h>
#include <hip/hip_bf16.h>
#include <math.h>

#define D 128
#define DH 64
#define CHUNK 2048
#define EPB 8
typedef __attribute__((ext_vector_type(8))) short bf16x8;
typedef __attribute__((ext_vector_type(4))) float f32x4;
constexpr float KREL = 3.141592653589793f / 1.5f;  // rel * (PI/1.5)

// ---- packed cos/sin table: pt[r*128 + 2c] = cos, pt[r*128 + 2c + 1] = sin ----
__global__ void k_tables(const float* __restrict__ rel_embed,
                         const float* __restrict__ loop_rel, int num_rel,
                         float* __restrict__ pt) {
    int i = blockIdx.x * blockDim.x + threadIdx.x;
    int total = (num_rel + 1) * DH;
    if (i >= total) return;
    int r = i / DH, c = i % DH;
    float v = (r < num_rel) ? rel_embed[r * DH + c] : loop_rel[c];
    float ang = v * KREL;
    pt[(size_t)r * D + 2 * c]     = cosf(ang);
    pt[(size_t)r * D + 2 * c + 1] = sinf(ang);
}

// ---- rel_out = (rel_embed @ w_rel) ----
__global__ void k_relout(const float* __restrict__ rel_embed,
                         const float* __restrict__ w_rel,
                         float* __restrict__ out2, int num_rel) {
    int i = blockIdx.x * blockDim.x + threadIdx.x;
    if (i >= num_rel * DH) return;
    int r = i / DH, j = i % DH;
    const float* a = rel_embed + r * DH;
    float acc = 0.f;
#pragma unroll 8
    for (int k = 0; k < DH; ++k) acc = fmaf(a[k], w_rel[k * DH + j], acc);
    out2[i] = acc;
}

// ---- pre-swizzle weights into MFMA B-fragment order (bf16), round-4 form ----
__global__ void k_wswz(const float* __restrict__ w_in, const float* __restrict__ w_out,
                       const float* __restrict__ w_loop, unsigned short* __restrict__ Bsw) {
    int i = blockIdx.x * blockDim.x + threadIdx.x;
    if (i >= 3 * 4 * 8 * 512) return;
    int j = i & 7;
    int lane = (i >> 3) & 63;
    int fid = i >> 9;
    int ct = fid & 7;
    int kt = (fid >> 3) & 3;
    int plane = fid >> 5;
    const float* Wp = (plane == 0) ? w_in : (plane == 1) ? w_out : w_loop;
    int k = kt * 32 + ((lane >> 4) << 3) + j;
    int col = ct * 16 + (lane & 15);
    __hip_bfloat16 h = __float2bfloat16(Wp[k * 128 + col]);
    Bsw[i] = __builtin_bit_cast(unsigned short, h);
}

// ---- degree histogram over 2N virtual rows (in-half then out-half) ----
__global__ void k_degree(const int* __restrict__ ei, int E2, int num_ent,
                         unsigned* __restrict__ deg) {
    int e = blockIdx.x * blockDim.x + threadIdx.x;
    if (e >= E2) return;
    int h = (e < (E2 >> 1)) ? 0 : 1;
    atomicAdd(&deg[h * num_ent + ei[e]], 1u);
}

// ---- hierarchical exclusive scan over 2N degrees -> rp ----
__global__ void k_scan1(const unsigned* __restrict__ deg, int n,
                        unsigned* __restrict__ rp, unsigned* __restrict__ partials) {
    __shared__ unsigned s[256];
    int tid = threadIdx.x;
    int base = blockIdx.x * CHUNK + tid * 8;
    unsigned v[8]; unsigned sum = 0;
#pragma unroll
    for (int i = 0; i < 8; ++i) { int g = base + i; v[i] = (g < n) ? deg[g] : 0u; sum += v[i]; }
    s[tid] = sum; __syncthreads();
    for (int off = 1; off < 256; off <<= 1) {
        unsigned t = (tid >= off) ? s[tid - off] : 0u;
        __syncthreads();
        s[tid] += t;
        __syncthreads();
    }
    if (tid == 255) partials[blockIdx.x] = s[255];
    unsigned run = (tid ? s[tid - 1] : 0u);
#pragma unroll
    for (int i = 0; i < 8; ++i) { int g = base + i; if (g < n) rp[g] = run; run += v[i]; }
}

__global__ void k_scan2(unsigned* __restrict__ partials, int nb) {
    __shared__ unsigned s[256];
    int tid = threadIdx.x;
    unsigned v = (tid < nb) ? partials[tid] : 0u;
    s[tid] = v; __syncthreads();
    for (int off = 1; off < 256; off <<= 1) {
        unsigned t = (tid >= off) ? s[tid - off] : 0u;
        __syncthreads();
        s[tid] += t;
        __syncthreads();
    }
    if (tid < nb) partials[tid] = (tid ? s[tid - 1] : 0u);
}

__global__ void k_scan3(unsigned* __restrict__ rp, int n,
                        const unsigned* __restrict__ partials) {
    unsigned add = partials[blockIdx.x];
    int base = blockIdx.x * CHUNK + threadIdx.x;
#pragma unroll
    for (int i = 0; i < 8; ++i) { int g = base + i * 256; if (g < n) rp[g] += add; }
}

// ---- scatter edges into CSR slots; payload (col, type, norm, vrow) ----
__global__ void k_fill(const int* __restrict__ ei, const int* __restrict__ et,
                       int E2, int num_ent,
                       const unsigned* __restrict__ deg, const unsigned* __restrict__ rp,
                       unsigned* __restrict__ fc, int4* __restrict__ csr) {
    int e = blockIdx.x * blockDim.x + threadIdx.x;
    if (e >= E2) return;
    int Eh = E2 >> 1;
    int h = (e < Eh) ? 0 : 1;
    int row = ei[e], col = ei[E2 + e], t = et[e];
    int idx = h * num_ent + row;
    unsigned dr = deg[idx], dc = deg[h * num_ent + col];
    float nrm = (dr > 0u && dc > 0u) ? rsqrtf((float)dr * (float)dc) : 0.f;
    unsigned slot = rp[idx] + atomicAdd(&fc[idx], 1u);
    csr[slot] = make_int4(col, t, __float_as_int(nrm), idx);
}

// ---- zero T rows with no edges (replaces the 102 MB memset) ----
__global__ void k_zrows(const unsigned* __restrict__ deg, int n2,
                        float* __restrict__ T) {
    int r = blockIdx.x * blockDim.x + threadIdx.x;
    if (r >= n2) return;
    if (deg[r] != 0u) return;
    float4 z = make_float4(0.f, 0.f, 0.f, 0.f);
    float4* p = (float4*)(T + (size_t)r * D);
#pragma unroll
    for (int i = 0; i < 32; ++i) p[i] = z;
}

// ---- row-ownership gather: 1 wave owns 16 virtual rows; plain stores to T ----
// (bisect build: accumulate identical to rounds 5-7, flush straight to global)
__global__ __launch_bounds__(256) void k_rowgather(
    const float* __restrict__ x, const int4* __restrict__ csr,
    const unsigned* __restrict__ rp, int E2, int n2,
    const float* __restrict__ pt, float* __restrict__ T) {
    int gwave = (int)((blockIdx.x * 256u + threadIdx.x) >> 6);
    int lane = threadIdx.x & 63;
    int vr0 = gwave * 16;
    if (vr0 >= n2) return;
    int vlim = min(vr0 + 16, n2);
    unsigned beg = rp[vr0];
    unsigned end = (vlim == n2) ? (unsigned)E2 : rp[vlim];
    if (beg >= end) return;

    int cur = -1;
    float a_re = 0.f, a_im = 0.f;
    for (unsigned s = beg; s < end; s += EPB) {
        int n = (int)min((unsigned)EPB, end - s);
        int4 m[EPB];
#pragma unroll
        for (int k = 0; k < EPB; ++k) {
            m[k] = csr[s + (k < n ? k : n - 1)];
            if (k >= n) m[k].z = 0;  // padded edges contribute 0
        }
        float re[EPB], im[EPB]; float2 cs2[EPB];
#pragma unroll
        for (int k = 0; k < EPB; ++k) {
            const float* xr = x + (size_t)m[k].x * D;
            re[k] = xr[lane];
            im[k] = xr[DH + lane];
            cs2[k] = *reinterpret_cast<const float2*>(pt + (size_t)m[k].y * D + 2 * lane);
        }
#pragma unroll
        for (int k = 0; k < EPB; ++k) {
            int trow = m[k].w;
            if (trow != cur) {  // wave-uniform
                if (cur >= 0) {
                    T[(size_t)cur * D + lane] = a_re;
                    T[(size_t)cur * D + DH + lane] = a_im;
                }
                cur = trow; a_re = a_im = 0.f;
            }
            float nm = __int_as_float(m[k].z);
            float nre = nm * re[k], nim = nm * im[k];
            a_re = fmaf(nre, cs2[k].x, fmaf(nim, cs2[k].y, a_re));
            a_im = fmaf(nre, cs2[k].y, fmaf(-nim, cs2[k].x, a_im));
        }
    }
    if (cur >= 0) {
        T[(size_t)cur * D + lane] = a_re;
        T[(size_t)cur * D + DH + lane] = a_im;
    }
}

// ---- MFMA combine (EXACT round-4 code): out = ([T_in|T_out|phi(x)]@W)/3 ----
__global__ __launch_bounds__(256) void k_combine(
    const float* __restrict__ T, const float* __restrict__ x,
    const unsigned short* __restrict__ Bsw, const float* __restrict__ pt,
    int num_rel, int num_ent, float* __restrict__ out) {
    int tid = threadIdx.x;
    int lane = tid & 63;
    int wid = tid >> 6;
    int base = blockIdx.x * 64 + wid * 16;
    int arow = base + (lane & 15);
    if (arow >= num_ent) arow = num_ent - 1;
    int khi = (lane >> 4) << 3;  // 0,8,16,24

    f32x4 acc[8];
    f32x4 zero = {0.f, 0.f, 0.f, 0.f};
#pragma unroll
    for (int i = 0; i < 8; ++i) acc[i] = zero;

    const float* ptL = pt + (size_t)num_rel * D;

    auto run_kt = [&](const float* av, int fid_base) {
        bf16x8 ah, al;
#pragma unroll
        for (int i = 0; i < 8; ++i) {
            unsigned b = __float_as_uint(av[i]);
            ah[i] = (short)(b >> 16);
            float hf = __uint_as_float(b & 0xFFFF0000u);
            al[i] = (short)(__float_as_uint(av[i] - hf) >> 16);
        }
#pragma unroll
        for (int ct = 0; ct < 8; ++ct) {
            const unsigned short* bp = Bsw + (((size_t)fid_base * 8 + ct) << 9) + (lane << 3);
            bf16x8 bfrag = *reinterpret_cast<const bf16x8*>(bp);
            acc[ct] = __builtin_amdgcn_mfma_f32_16x16x32_bf16(ah, bfrag, acc[ct], 0, 0, 0);
            acc[ct] = __builtin_amdgcn_mfma_f32_16x16x32_bf16(al, bfrag, acc[ct], 0, 0, 0);
        }
    };

    // planes 0,1: T_in / T_out (stored as [2N][128])
#pragma unroll
    for (int plane = 0; plane < 2; ++plane) {
        const float* Ab = T + ((size_t)plane * num_ent + arow) * D;
#pragma unroll
        for (int kt = 0; kt < 4; ++kt) {
            float4 q0 = *reinterpret_cast<const float4*>(Ab + kt * 32 + khi);
            float4 q1 = *reinterpret_cast<const float4*>(Ab + kt * 32 + khi + 4);
            float av[8] = {q0.x, q0.y, q0.z, q0.w, q1.x, q1.y, q1.z, q1.w};
            run_kt(av, plane * 4 + kt);
        }
    }
    // plane 2: loop transform computed on the fly
    {
        const float* xr = x + (size_t)arow * D;
#pragma unroll
        for (int kt = 0; kt < 4; ++kt) {
            int kp = ((kt & 1) << 5) + khi;  // k' in [0,64)
            float4 r0 = *reinterpret_cast<const float4*>(xr + kp);
            float4 r1 = *reinterpret_cast<const float4*>(xr + kp + 4);
            float4 i0 = *reinterpret_cast<const float4*>(xr + DH + kp);
            float4 i1 = *reinterpret_cast<const float4*>(xr + DH + kp + 4);
            float rr[8] = {r0.x, r0.y, r0.z, r0.w, r1.x, r1.y, r1.z, r1.w};
            float ii[8] = {i0.x, i0.y, i0.z, i0.w, i1.x, i1.y, i1.z, i1.w};
            float av[8];
#pragma unroll
            for (int j = 0; j < 8; ++j) {
                float2 cs = *reinterpret_cast<const float2*>(ptL + 2 * (kp + j));
                av[j] = (kt < 2) ? fmaf(rr[j], cs.x, ii[j] * cs.y)
                                 : (rr[j] * cs.y - ii[j] * cs.x);
            }
            run_kt(av, 8 + kt);
        }
    }
    // store: C/D layout col=lane&15, row=(lane>>4)*4+reg
    const float third = 1.0f / 3.0f;
    int rbase = base + ((lane >> 4) << 2);
    int colb = lane & 15;
#pragma unroll
    for (int ct = 0; ct < 8; ++ct) {
#pragma unroll
        for (int jj = 0; jj < 4; ++jj) {
            int g = rbase + jj;
            if (g < num_ent) out[(size_t)g * D + ct * 16 + colb] = acc[ct][jj] * third;
        }
    }
}

extern "C" void kernel_launch(void* const* d_in, const int* in_sizes, int n_in,
                              void* d_out, int out_size, void* d_ws, size_t ws_size,
                              hipStream_t stream) {
    const float* x         = (const float*)d_in[0];
    const int*   ei        = (const int*)d_in[1];
    const int*   et        = (const int*)d_in[2];
    const float* rel_embed = (const float*)d_in[3];
    const float* w_loop    = (const float*)d_in[4];
    const float* w_in      = (const float*)d_in[5];
    const float* w_out     = (const float*)d_in[6];
    const float* w_rel     = (const float*)d_in[7];
    const float* loop_rel  = (const float*)d_in[8];
    float* out = (float*)d_out;

    int num_ent = in_sizes[0] / D;
    int E2      = in_sizes[2];
    int num_rel = in_sizes[3] / DH;
    float* out2 = out + (size_t)num_ent * D;

    int n2 = 2 * num_ent;
    char* ws = (char*)d_ws;
    unsigned* deg = (unsigned*)ws;                 // 2N
    unsigned* fc  = deg + n2;                      // 2N (adjacent: one memset)
    unsigned* rp  = fc + n2;                       // 2N
    unsigned* partials = rp + n2;                  // 256
    size_t off = (size_t)(3 * n2 + 256) * sizeof(unsigned);
    off = (off + 15) & ~(size_t)15;
    int4* csr = (int4*)(ws + off);                 // E2 int4
    float* pt = (float*)(csr + E2);                // (num_rel+1)*128 floats
    unsigned short* Bsw = (unsigned short*)(pt + (size_t)(num_rel + 1) * D);  // 3*4*8*512
    float* T = (float*)(Bsw + 3 * 4 * 8 * 512);    // 2N*128 floats

    hipMemsetAsync(deg, 0, (size_t)2 * n2 * sizeof(unsigned), stream);

    int tbl = (num_rel + 1) * DH;
    k_tables<<<(tbl + 255) / 256, 256, 0, stream>>>(rel_embed, loop_rel, num_rel, pt);
    k_wswz<<<(3 * 4 * 8 * 512 + 255) / 256, 256, 0, stream>>>(w_in, w_out, w_loop, Bsw);
    k_relout<<<(num_rel * DH + 255) / 256, 256, 0, stream>>>(rel_embed, w_rel, out2, num_rel);
    k_degree<<<(E2 + 255) / 256, 256, 0, stream>>>(ei, E2, num_ent, deg);

    int nb1 = (n2 + CHUNK - 1) / CHUNK;
    k_scan1<<<nb1, 256, 0, stream>>>(deg, n2, rp, partials);
    k_scan2<<<1, 256, 0, stream>>>(partials, nb1);
    k_scan3<<<nb1, 256, 0, stream>>>(rp, n2, partials);

    k_fill<<<(E2 + 255) / 256, 256, 0, stream>>>(ei, et, E2, num_ent, deg, rp, fc, csr);
    k_zrows<<<(n2 + 255) / 256, 256, 0, stream>>>(deg, n2, (float*)T);

    int nwaves = (n2 + 15) / 16;
    int gblocks = (nwaves * 64 + 255) / 256;
    k_rowgather<<<gblocks, 256, 0, stream>>>(x, csr, rp, E2, n2, pt, T);

    int cb = (num_ent + 63) / 64;
    k_combine<<<cb, 256, 0, stream>>>(T, x, Bsw, pt, num_rel, num_ent, out);
}

// Round 10
// 250.968 us; speedup vs baseline: 3.0395x; 1.1716x over previous
//
#include <hip/hip_runtime.h>
#include <hip/hip_bf16.h>
#include <math.h>

#define D 128
#define DH 64
#define CHUNK 2048
#define EPB 8
typedef __attribute__((ext_vector_type(8))) short bf16x8;
typedef __attribute__((ext_vector_type(4))) float f32x4;
constexpr float KREL = 3.141592653589793f / 1.5f;  // rel * (PI/1.5)

static __device__ __forceinline__ unsigned short bf16u(float f) {
    return __builtin_bit_cast(unsigned short, __float2bfloat16(f));
}

// ---- packed cos/sin table: pt[r*128 + 2c] = cos, pt[r*128 + 2c + 1] = sin ----
__global__ void k_tables(const float* __restrict__ rel_embed,
                         const float* __restrict__ loop_rel, int num_rel,
                         float* __restrict__ pt) {
    int i = blockIdx.x * blockDim.x + threadIdx.x;
    int total = (num_rel + 1) * DH;
    if (i >= total) return;
    int r = i / DH, c = i % DH;
    float v = (r < num_rel) ? rel_embed[r * DH + c] : loop_rel[c];
    float ang = v * KREL;
    pt[(size_t)r * D + 2 * c]     = cosf(ang);
    pt[(size_t)r * D + 2 * c + 1] = sinf(ang);
}

// ---- rel_out = (rel_embed @ w_rel) ----
__global__ void k_relout(const float* __restrict__ rel_embed,
                         const float* __restrict__ w_rel,
                         float* __restrict__ out2, int num_rel) {
    int i = blockIdx.x * blockDim.x + threadIdx.x;
    if (i >= num_rel * DH) return;
    int r = i / DH, j = i % DH;
    const float* a = rel_embed + r * DH;
    float acc = 0.f;
#pragma unroll 8
    for (int k = 0; k < DH; ++k) acc = fmaf(a[k], w_rel[k * DH + j], acc);
    out2[i] = acc;
}

// ---- pre-swizzle weights into MFMA B-fragment order (bf16) with k-PERMUTATION
// matching interleaved A: A'[k'] = msg[(k'>>1) + (k'&1)*64]. B'[k'] = W[perm(k')].
__global__ void k_wswz(const float* __restrict__ w_in, const float* __restrict__ w_out,
                       const float* __restrict__ w_loop, unsigned short* __restrict__ Bsw) {
    int i = blockIdx.x * blockDim.x + threadIdx.x;
    if (i >= 3 * 4 * 8 * 512) return;
    int j = i & 7;
    int lane = (i >> 3) & 63;
    int fid = i >> 9;
    int ct = fid & 7;
    int kt = (fid >> 3) & 3;
    int plane = fid >> 5;
    const float* Wp = (plane == 0) ? w_in : (plane == 1) ? w_out : w_loop;
    int kp = kt * 32 + ((lane >> 4) << 3) + j;      // k' in interleaved space
    int orig = (kp >> 1) + (kp & 1) * DH;           // bijective perm
    int col = ct * 16 + (lane & 15);
    Bsw[i] = bf16u(Wp[orig * 128 + col]);
}

// ---- degree histogram over 2N virtual rows (in-half then out-half) ----
__global__ void k_degree(const int* __restrict__ ei, int E2, int num_ent,
                         unsigned* __restrict__ deg) {
    int e = blockIdx.x * blockDim.x + threadIdx.x;
    if (e >= E2) return;
    int h = (e < (E2 >> 1)) ? 0 : 1;
    atomicAdd(&deg[h * num_ent + ei[e]], 1u);
}

// ---- hierarchical exclusive scan over 2N degrees -> rp ----
__global__ void k_scan1(const unsigned* __restrict__ deg, int n,
                        unsigned* __restrict__ rp, unsigned* __restrict__ partials) {
    __shared__ unsigned s[256];
    int tid = threadIdx.x;
    int base = blockIdx.x * CHUNK + tid * 8;
    unsigned v[8]; unsigned sum = 0;
#pragma unroll
    for (int i = 0; i < 8; ++i) { int g = base + i; v[i] = (g < n) ? deg[g] : 0u; sum += v[i]; }
    s[tid] = sum; __syncthreads();
    for (int off = 1; off < 256; off <<= 1) {
        unsigned t = (tid >= off) ? s[tid - off] : 0u;
        __syncthreads();
        s[tid] += t;
        __syncthreads();
    }
    if (tid == 255) partials[blockIdx.x] = s[255];
    unsigned run = (tid ? s[tid - 1] : 0u);
#pragma unroll
    for (int i = 0; i < 8; ++i) { int g = base + i; if (g < n) rp[g] = run; run += v[i]; }
}

__global__ void k_scan2(unsigned* __restrict__ partials, int nb) {
    __shared__ unsigned s[256];
    int tid = threadIdx.x;
    unsigned v = (tid < nb) ? partials[tid] : 0u;
    s[tid] = v; __syncthreads();
    for (int off = 1; off < 256; off <<= 1) {
        unsigned t = (tid >= off) ? s[tid - off] : 0u;
        __syncthreads();
        s[tid] += t;
        __syncthreads();
    }
    if (tid < nb) partials[tid] = (tid ? s[tid - 1] : 0u);
}

__global__ void k_scan3(unsigned* __restrict__ rp, int n,
                        const unsigned* __restrict__ partials) {
    unsigned add = partials[blockIdx.x];
    int base = blockIdx.x * CHUNK + threadIdx.x;
#pragma unroll
    for (int i = 0; i < 8; ++i) { int g = base + i * 256; if (g < n) rp[g] += add; }
}

// ---- scatter edges into CSR slots; payload (col, type, norm, vrow) ----
__global__ void k_fill(const int* __restrict__ ei, const int* __restrict__ et,
                       int E2, int num_ent,
                       const unsigned* __restrict__ deg, const unsigned* __restrict__ rp,
                       unsigned* __restrict__ fc, int4* __restrict__ csr) {
    int e = blockIdx.x * blockDim.x + threadIdx.x;
    if (e >= E2) return;
    int Eh = E2 >> 1;
    int h = (e < Eh) ? 0 : 1;
    int row = ei[e], col = ei[E2 + e], t = et[e];
    int idx = h * num_ent + row;
    unsigned dr = deg[idx], dc = deg[h * num_ent + col];
    float nrm = (dr > 0u && dc > 0u) ? rsqrtf((float)dr * (float)dc) : 0.f;
    unsigned slot = rp[idx] + atomicAdd(&fc[idx], 1u);
    csr[slot] = make_int4(col, t, __float_as_int(nrm), idx);
}

// ---- zero T2 rows with no edges ----
__global__ void k_zrows(const unsigned* __restrict__ deg, int n2,
                        unsigned short* __restrict__ T2) {
    int r = blockIdx.x * blockDim.x + threadIdx.x;
    if (r >= n2) return;
    if (deg[r] != 0u) return;
    uint4 z = make_uint4(0u, 0u, 0u, 0u);
    uint4* p = (uint4*)(T2 + (size_t)r * D);
#pragma unroll
    for (int i = 0; i < 16; ++i) p[i] = z;
}

// ---- row-ownership gather: 1 wave owns 16 virtual rows; packed bf16 stores ----
// T2[row][2l] = bf16(re_l), T2[row][2l+1] = bf16(im_l): one dword store per lane.
__global__ __launch_bounds__(256) void k_rowgather(
    const float* __restrict__ x, const int4* __restrict__ csr,
    const unsigned* __restrict__ rp, int E2, int n2,
    const float* __restrict__ pt, unsigned short* __restrict__ T2) {
    int gwave = (int)((blockIdx.x * 256u + threadIdx.x) >> 6);
    int lane = threadIdx.x & 63;
    int vr0 = gwave * 16;
    if (vr0 >= n2) return;
    int vlim = min(vr0 + 16, n2);
    unsigned beg = rp[vr0];
    unsigned end = (vlim == n2) ? (unsigned)E2 : rp[vlim];
    if (beg >= end) return;

    int cur = -1;
    float a_re = 0.f, a_im = 0.f;
    for (unsigned s = beg; s < end; s += EPB) {
        int n = (int)min((unsigned)EPB, end - s);
        int4 m[EPB];
#pragma unroll
        for (int k = 0; k < EPB; ++k) {
            m[k] = csr[s + (k < n ? k : n - 1)];
            if (k >= n) m[k].z = 0;  // padded edges contribute 0
        }
        float re[EPB], im[EPB]; float2 cs2[EPB];
#pragma unroll
        for (int k = 0; k < EPB; ++k) {
            const float* xr = x + (size_t)m[k].x * D;
            re[k] = xr[lane];
            im[k] = xr[DH + lane];
            cs2[k] = *reinterpret_cast<const float2*>(pt + (size_t)m[k].y * D + 2 * lane);
        }
#pragma unroll
        for (int k = 0; k < EPB; ++k) {
            int trow = m[k].w;
            if (trow != cur) {  // wave-uniform
                if (cur >= 0) {
                    unsigned pack = (unsigned)bf16u(a_re) | ((unsigned)bf16u(a_im) << 16);
                    ((unsigned*)(T2 + (size_t)cur * D))[lane] = pack;
                }
                cur = trow; a_re = a_im = 0.f;
            }
            float nm = __int_as_float(m[k].z);
            float nre = nm * re[k], nim = nm * im[k];
            a_re = fmaf(nre, cs2[k].x, fmaf(nim, cs2[k].y, a_re));
            a_im = fmaf(nre, cs2[k].y, fmaf(-nim, cs2[k].x, a_im));
        }
    }
    if (cur >= 0) {
        unsigned pack = (unsigned)bf16u(a_re) | ((unsigned)bf16u(a_im) << 16);
        ((unsigned*)(T2 + (size_t)cur * D))[lane] = pack;
    }
}

// ---- MFMA combine: A-fragments load directly as bf16 from interleaved T2 ----
__global__ __launch_bounds__(256) void k_combine(
    const unsigned short* __restrict__ T2, const float* __restrict__ x,
    const unsigned short* __restrict__ Bsw, const float* __restrict__ pt,
    int num_rel, int num_ent, float* __restrict__ out) {
    int tid = threadIdx.x;
    int lane = tid & 63;
    int wid = tid >> 6;
    int base = blockIdx.x * 64 + wid * 16;
    int arow = base + (lane & 15);
    if (arow >= num_ent) arow = num_ent - 1;
    int khi = (lane >> 4) << 3;  // 0,8,16,24

    f32x4 acc[8];
    f32x4 zero = {0.f, 0.f, 0.f, 0.f};
#pragma unroll
    for (int i = 0; i < 8; ++i) acc[i] = zero;

    const float* ptL = pt + (size_t)num_rel * D;

    auto run_kt = [&](bf16x8 afrag, int fid_base) {
#pragma unroll
        for (int ct = 0; ct < 8; ++ct) {
            const unsigned short* bp = Bsw + (((size_t)fid_base * 8 + ct) << 9) + (lane << 3);
            bf16x8 bfrag = *reinterpret_cast<const bf16x8*>(bp);
            acc[ct] = __builtin_amdgcn_mfma_f32_16x16x32_bf16(afrag, bfrag, acc[ct], 0, 0, 0);
        }
    };

    // planes 0,1: T2 (interleaved bf16, A-ready)
#pragma unroll
    for (int plane = 0; plane < 2; ++plane) {
        const unsigned short* Ab = T2 + ((size_t)plane * num_ent + arow) * D;
#pragma unroll
        for (int kt = 0; kt < 4; ++kt) {
            bf16x8 afrag = *reinterpret_cast<const bf16x8*>(Ab + kt * 32 + khi);
            run_kt(afrag, plane * 4 + kt);
        }
    }
    // plane 2: loop transform on the fly, packed interleaved
    {
        const float* xr = x + (size_t)arow * D;
#pragma unroll
        for (int kt = 0; kt < 4; ++kt) {
            int c0 = (kt * 32 + khi) >> 1;  // multiple of 4, in [0,64)
            float4 xre = *reinterpret_cast<const float4*>(xr + c0);
            float4 xim = *reinterpret_cast<const float4*>(xr + DH + c0);
            float4 cs0 = *reinterpret_cast<const float4*>(ptL + 2 * c0);
            float4 cs1 = *reinterpret_cast<const float4*>(ptL + 2 * c0 + 4);
            float rr[4] = {xre.x, xre.y, xre.z, xre.w};
            float ii[4] = {xim.x, xim.y, xim.z, xim.w};
            float cc[4] = {cs0.x, cs0.z, cs1.x, cs1.z};
            float ss[4] = {cs0.y, cs0.w, cs1.y, cs1.w};
            bf16x8 afrag;
#pragma unroll
            for (int q = 0; q < 4; ++q) {
                afrag[2 * q]     = (short)bf16u(fmaf(rr[q], cc[q], ii[q] * ss[q]));
                afrag[2 * q + 1] = (short)bf16u(rr[q] * ss[q] - ii[q] * cc[q]);
            }
            run_kt(afrag, 8 + kt);
        }
    }
    // store: C/D layout col=lane&15, row=(lane>>4)*4+reg
    const float third = 1.0f / 3.0f;
    int rbase = base + ((lane >> 4) << 2);
    int colb = lane & 15;
#pragma unroll
    for (int ct = 0; ct < 8; ++ct) {
#pragma unroll
        for (int jj = 0; jj < 4; ++jj) {
            int g = rbase + jj;
            if (g < num_ent) out[(size_t)g * D + ct * 16 + colb] = acc[ct][jj] * third;
        }
    }
}

extern "C" void kernel_launch(void* const* d_in, const int* in_sizes, int n_in,
                              void* d_out, int out_size, void* d_ws, size_t ws_size,
                              hipStream_t stream) {
    const float* x         = (const float*)d_in[0];
    const int*   ei        = (const int*)d_in[1];
    const int*   et        = (const int*)d_in[2];
    const float* rel_embed = (const float*)d_in[3];
    const float* w_loop    = (const float*)d_in[4];
    const float* w_in      = (const float*)d_in[5];
    const float* w_out     = (const float*)d_in[6];
    const float* w_rel     = (const float*)d_in[7];
    const float* loop_rel  = (const float*)d_in[8];
    float* out = (float*)d_out;

    int num_ent = in_sizes[0] / D;
    int E2      = in_sizes[2];
    int num_rel = in_sizes[3] / DH;
    float* out2 = out + (size_t)num_ent * D;

    int n2 = 2 * num_ent;
    char* ws = (char*)d_ws;
    unsigned* deg = (unsigned*)ws;                 // 2N
    unsigned* fc  = deg + n2;                      // 2N (adjacent: one memset)
    unsigned* rp  = fc + n2;                       // 2N
    unsigned* partials = rp + n2;                  // 256
    size_t off = (size_t)(3 * n2 + 256) * sizeof(unsigned);
    off = (off + 15) & ~(size_t)15;
    int4* csr = (int4*)(ws + off);                 // E2 int4
    float* pt = (float*)(csr + E2);                // (num_rel+1)*128 floats
    unsigned short* Bsw = (unsigned short*)(pt + (size_t)(num_rel + 1) * D);  // 3*4*8*512
    unsigned short* T2 = Bsw + (size_t)3 * 4 * 8 * 512;  // 2N*128 bf16

    hipMemsetAsync(deg, 0, (size_t)2 * n2 * sizeof(unsigned), stream);

    int tbl = (num_rel + 1) * DH;
    k_tables<<<(tbl + 255) / 256, 256, 0, stream>>>(rel_embed, loop_rel, num_rel, pt);
    k_wswz<<<(3 * 4 * 8 * 512 + 255) / 256, 256, 0, stream>>>(w_in, w_out, w_loop, Bsw);
    k_relout<<<(num_rel * DH + 255) / 256, 256, 0, stream>>>(rel_embed, w_rel, out2, num_rel);
    k_degree<<<(E2 + 255) / 256, 256, 0, stream>>>(ei, E2, num_ent, deg);

    int nb1 = (n2 + CHUNK - 1) / CHUNK;
    k_scan1<<<nb1, 256, 0, stream>>>(deg, n2, rp, partials);
    k_scan2<<<1, 256, 0, stream>>>(partials, nb1);
    k_scan3<<<nb1, 256, 0, stream>>>(rp, n2, partials);

    k_fill<<<(E2 + 255) / 256, 256, 0, stream>>>(ei, et, E2, num_ent, deg, rp, fc, csr);
    k_zrows<<<(n2 + 255) / 256, 256, 0, stream>>>(deg, n2, T2);

    int nwaves = (n2 + 15) / 16;
    int gblocks = (nwaves * 64 + 255) / 256;
    k_rowgather<<<gblocks, 256, 0, stream>>>(x, csr, rp, E2, n2, pt, T2);

    int cb = (num_ent + 63) / 64;
    k_combine<<<cb, 256, 0, stream>>>(T2, x, Bsw, pt, num_rel, num_ent, out);
}